// Round 1
// baseline (76.769 us; speedup 1.0000x reference)
//
#include <hip/hip_runtime.h>
#include <math.h>

// Problem constants (fixed by the reference)
#define B_ 512
#define K_ 1024
#define D_ 256
#define EPS_ 1e-6f

// Tiling: BM x BN output tile per block, BK K-chunk
#define BM 64
#define BN 32
#define BK 32
#define XLD (BM + 4)   // 68: row stride 272B -> 16B-aligned float4 reads, bank-stride 4
#define PLD (BN + 4)   // 36: row stride 144B -> 8B-aligned float2 reads

__global__ __launch_bounds__(256) void hyp_mlr_kernel(
    const float* __restrict__ x,   // [B, D]
    const float* __restrict__ p,   // [K, D]
    const float* __restrict__ a,   // [K, D]
    float* __restrict__ out)       // [B, K]
{
    __shared__ __align__(16) float Xs[BK][XLD];  // transposed: Xs[d][b]
    __shared__ __align__(16) float Ps[BK][PLD];  // transposed: Ps[d][k]
    __shared__ __align__(16) float As[BK][PLD];

    const int t  = threadIdx.x;
    const int tx = t & 15;    // k-dim: 2 cols each
    const int ty = t >> 4;    // b-dim: 4 rows each
    const int k0 = blockIdx.x * BN;
    const int b0 = blockIdx.y * BM;

    // staging-load mapping: one float4 per (row-chunk)
    const int lrow = t >> 3;        // 0..31
    const int lcol = (t & 7) * 4;   // 0,4,...,28

    float dotp[4][2] = {{0.f,0.f},{0.f,0.f},{0.f,0.f},{0.f,0.f}};
    float dota[4][2] = {{0.f,0.f},{0.f,0.f},{0.f,0.f},{0.f,0.f}};
    float x2a[4] = {0.f,0.f,0.f,0.f};
    float p2a[2] = {0.f,0.f};
    float a2a[2] = {0.f,0.f};
    float paa[2] = {0.f,0.f};

    for (int kk = 0; kk < D_; kk += BK) {
        __syncthreads();  // protect LDS from previous iteration's readers
        // X tile: 64 rows x 32 cols -> 2 float4 per thread, stored transposed
        {
            float4 v0 = *(const float4*)&x[(b0 + lrow)      * D_ + kk + lcol];
            float4 v1 = *(const float4*)&x[(b0 + lrow + 32) * D_ + kk + lcol];
            Xs[lcol + 0][lrow] = v0.x;
            Xs[lcol + 1][lrow] = v0.y;
            Xs[lcol + 2][lrow] = v0.z;
            Xs[lcol + 3][lrow] = v0.w;
            Xs[lcol + 0][lrow + 32] = v1.x;
            Xs[lcol + 1][lrow + 32] = v1.y;
            Xs[lcol + 2][lrow + 32] = v1.z;
            Xs[lcol + 3][lrow + 32] = v1.w;
        }
        // P tile: 32 rows x 32 cols -> 1 float4 per thread
        {
            float4 v = *(const float4*)&p[(k0 + lrow) * D_ + kk + lcol];
            Ps[lcol + 0][lrow] = v.x;
            Ps[lcol + 1][lrow] = v.y;
            Ps[lcol + 2][lrow] = v.z;
            Ps[lcol + 3][lrow] = v.w;
        }
        // A tile
        {
            float4 v = *(const float4*)&a[(k0 + lrow) * D_ + kk + lcol];
            As[lcol + 0][lrow] = v.x;
            As[lcol + 1][lrow] = v.y;
            As[lcol + 2][lrow] = v.z;
            As[lcol + 3][lrow] = v.w;
        }
        __syncthreads();

#pragma unroll
        for (int j = 0; j < BK; ++j) {
            float4 xv = *(const float4*)&Xs[j][ty * 4];
            float2 pv = *(const float2*)&Ps[j][tx * 2];
            float2 av = *(const float2*)&As[j][tx * 2];
            float xr[4] = {xv.x, xv.y, xv.z, xv.w};
            float pr[2] = {pv.x, pv.y};
            float ar[2] = {av.x, av.y};
#pragma unroll
            for (int i = 0; i < 4; ++i) {
                x2a[i] = fmaf(xr[i], xr[i], x2a[i]);
#pragma unroll
                for (int c = 0; c < 2; ++c) {
                    dotp[i][c] = fmaf(xr[i], pr[c], dotp[i][c]);
                    dota[i][c] = fmaf(xr[i], ar[c], dota[i][c]);
                }
            }
#pragma unroll
            for (int c = 0; c < 2; ++c) {
                p2a[c] = fmaf(pr[c], pr[c], p2a[c]);
                a2a[c] = fmaf(ar[c], ar[c], a2a[c]);
                paa[c] = fmaf(pr[c], ar[c], paa[c]);
            }
        }
    }

    // Epilogue: Ganea hyperbolic MLR logit from the 6 scalars.
    //   u = -p, v = x:
    //   alpha = 1 + 2<u,v> + |v|^2 = 1 - 2 dot + x2      (coeff of u in num)
    //   beta  = 1 - |u|^2          = 1 - p2              (coeff of v in num)
    //   gamma = 1 + 2<u,v> + |u|^2|v|^2 + EPS = 1 - 2 dot + p2*x2 + EPS
    //   z2 = (alpha^2 p2 - 2 alpha beta dot + beta^2 x2) / gamma^2
    //   za = <z, beta*a> = beta (beta*xa - alpha*pa) / gamma
    //   na = beta*sqrt(a2); lam = 2/(beta+EPS)
    //   logit = lam * na * asinh(2 za / ((1 - z2) na + EPS))
#pragma unroll
    for (int i = 0; i < 4; ++i) {
        const int b = b0 + ty * 4 + i;
        const float x2 = x2a[i];
        float res[2];
#pragma unroll
        for (int c = 0; c < 2; ++c) {
            const float p2 = p2a[c];
            const float a2 = a2a[c];
            const float pa = paa[c];
            const float dt = dotp[i][c];
            const float xa = dota[i][c];

            const float beta  = 1.0f - p2;
            const float alpha = 1.0f + x2 - 2.0f * dt;
            const float den   = 1.0f - 2.0f * dt + p2 * x2;
            const float rg    = 1.0f / (den + EPS_);
            const float z2    = (alpha * alpha * p2 - 2.0f * alpha * beta * dt
                                 + beta * beta * x2) * rg * rg;
            const float za    = beta * (beta * xa - alpha * pa) * rg;
            const float na    = beta * sqrtf(a2);
            const float lam   = 2.0f / (beta + EPS_);
            const float arg   = 2.0f * za / ((1.0f - z2) * na + EPS_);
            res[c] = lam * na * asinhf(arg);
        }
        *(float2*)&out[b * K_ + k0 + tx * 2] = make_float2(res[0], res[1]);
    }
}

extern "C" void kernel_launch(void* const* d_in, const int* in_sizes, int n_in,
                              void* d_out, int out_size, void* d_ws, size_t ws_size,
                              hipStream_t stream) {
    const float* x = (const float*)d_in[0];  // [512, 256]
    const float* p = (const float*)d_in[1];  // [1024, 256]
    const float* a = (const float*)d_in[2];  // [1024, 256]
    float* out = (float*)d_out;              // [512, 1024]

    dim3 grid(K_ / BN, B_ / BM);   // (32, 8) = 256 blocks, 1 per CU
    dim3 block(256);
    hyp_mlr_kernel<<<grid, block, 0, stream>>>(x, p, a, out);
}